// Round 13
// baseline (190.394 us; speedup 1.0000x reference)
//
#include <hip/hip_runtime.h>
#include <hip/hip_bf16.h>

// Problem constants
#define B_ 4
#define T_ 2048
#define E_ 1024
#define H_ 16
#define DH_ 64

typedef __bf16 bf16x8 __attribute__((ext_vector_type(8)));
typedef __bf16 bf16x4 __attribute__((ext_vector_type(4)));
typedef float f32x4 __attribute__((ext_vector_type(4)));

#define EXP2F(x) __builtin_amdgcn_exp2f(x)
#define NEG_INF (-__builtin_inff())

// async global->LDS, 16B per lane: lane l writes lds_base + l*16
__device__ __forceinline__ void async_copy16(const __bf16* g, __bf16* l) {
    __builtin_amdgcn_global_load_lds(
        (const __attribute__((address_space(1))) unsigned int*)g,
        (__attribute__((address_space(3))) unsigned int*)l, 16, 0, 0);
}

// ---------------------------------------------------------------- fused casts
__global__ void cast_all(const float* __restrict__ x,
                         const float* __restrict__ Wq, const float* __restrict__ Wk,
                         const float* __restrict__ Wv, const float* __restrict__ Wp,
                         __bf16* __restrict__ xb, __bf16* __restrict__ wcat,
                         __bf16* __restrict__ wpb) {
    int tid = blockIdx.x * blockDim.x + threadIdx.x;   // grid covers 2,097,152
    {
        int i = tid * 4;                                // x: B*T*E = 8,388,608
        float4 f = *reinterpret_cast<const float4*>(x + i);
        bf16x4 o = { (__bf16)f.x, (__bf16)f.y, (__bf16)f.z, (__bf16)f.w };
        *reinterpret_cast<bf16x4*>(xb + i) = o;
    }
    if (tid < 262144) {                                 // Wp: 1,048,576
        int i = tid * 4;
        float4 f = *reinterpret_cast<const float4*>(Wp + i);
        bf16x4 o = { (__bf16)f.x, (__bf16)f.y, (__bf16)f.z, (__bf16)f.w };
        *reinterpret_cast<bf16x4*>(wpb + i) = o;
    }
    if (tid < 786432) {                                 // wcat: 3072*1024
        int i = tid * 4;
        int e = i & (E_ - 1);                           // 4 consecutive e
        int n = i >> 10;
        int rem = n & 1023, h = rem >> 6, d = rem & 63;
        const float* src = (n < 1024) ? Wq : (n < 2048 ? Wk : Wv);
        const float* sp = src + ((long)((h << 10) + e)) * DH_ + d;
        bf16x4 o = { (__bf16)sp[0], (__bf16)sp[DH_], (__bf16)sp[2 * DH_], (__bf16)sp[3 * DH_] };
        *reinterpret_cast<bf16x4*>(wcat + i) = o;
    }
}

// ---------------------------------------------------------------- GEMM v3 (C = A * Bt^T)
// 256x128 tile, BK=64, 8 waves (4M x 2N), TRIPLE-buffered LDS (144 KB),
// counted vmcnt(6): iter t computes buf[t%3] while staging tile t+2 into
// buf[(t+2)%3] (read by nobody until t+2 -> race-free by construction).
// One barrier per K-tile; loads never drain to 0 in the main loop.
// MODE 1: C[m][N] f32 + bias.   MODE 3: QKV epilogue -> q/k [bh][t][d], vt [bh][d][t].
template<int MODE>
__global__ __launch_bounds__(512, 2) void gemm256(
    const __bf16* __restrict__ A, const __bf16* __restrict__ Bt,
    float* __restrict__ Cf, const float* __restrict__ bias,
    __bf16* __restrict__ oq, __bf16* __restrict__ ok, __bf16* __restrict__ ovt,
    int K, int N) {

    __shared__ __bf16 As[3][256][64];   // 96 KB
    __shared__ __bf16 Bs[3][128][64];   // 48 KB

    int tid = threadIdx.x, lane = tid & 63, wid = tid >> 6;   // wid 0..7
    int wm = wid >> 1, wn = wid & 1;
    int rlo = lane & 15, rhi = lane >> 4;
    int srow8 = tid >> 3;              // row within a 64-row staging line
    int sc = tid & 7;                  // chunk within row

    const __bf16* Ab = A + (long)blockIdx.x * 256 * K;
    const __bf16* Bb = Bt + (long)blockIdx.y * 128 * K;

    f32x4 acc[4][4] = {};
    int NT = K >> 6;                   // 16

    // staging: line g covers rows [g*64, g*64+64); wave's dst is wave-uniform;
    // global source chunk pre-swizzled with the involution c ^ (row&7)
    auto STAGE_A = [&](int buf, int t, int g) {
        int gr = g * 64 + srow8;
        int scs = sc ^ (gr & 7);
        async_copy16(Ab + (long)gr * K + t * 64 + scs * 8, &As[buf][g * 64 + wid * 8][0]);
    };
    auto STAGE_B = [&](int buf, int t, int g) {
        int gr = g * 64 + srow8;
        int scs = sc ^ (gr & 7);
        async_copy16(Bb + (long)gr * K + t * 64 + scs * 8, &Bs[buf][g * 64 + wid * 8][0]);
    };

    // one phase: operands for kstep kk from buf, 16 MFMA
    auto PHASE = [&](int buf, int kk) {
        bf16x8 af[4], bf[4];
        #pragma unroll
        for (int mi = 0; mi < 4; mi++) {
            int r = wm * 64 + mi * 16 + rlo;
            af[mi] = *reinterpret_cast<const bf16x8*>(
                &As[buf][r][((kk * 4 + rhi) ^ (r & 7)) * 8]);
        }
        #pragma unroll
        for (int ni = 0; ni < 4; ni++) {
            int rn = wn * 64 + ni * 16 + rlo;
            bf[ni] = *reinterpret_cast<const bf16x8*>(
                &Bs[buf][rn][((kk * 4 + rhi) ^ (rn & 7)) * 8]);
        }
        __builtin_amdgcn_s_setprio(1);
        #pragma unroll
        for (int mi = 0; mi < 4; mi++)
            #pragma unroll
            for (int ni = 0; ni < 4; ni++)
                acc[mi][ni] = __builtin_amdgcn_mfma_f32_16x16x32_bf16(
                    af[mi], bf[ni], acc[mi][ni], 0, 0, 0);
        __builtin_amdgcn_s_setprio(0);
    };

    // prologue: stage tiles 0 and 1 (6 loads each); wait for tile 0 only
    #pragma unroll
    for (int g = 0; g < 4; g++) STAGE_A(0, 0, g);
    #pragma unroll
    for (int g = 0; g < 2; g++) STAGE_B(0, 0, g);
    #pragma unroll
    for (int g = 0; g < 4; g++) STAGE_A(1, 1, g);
    #pragma unroll
    for (int g = 0; g < 2; g++) STAGE_B(1, 1, g);
    asm volatile("s_waitcnt vmcnt(6)" ::: "memory");
    asm volatile("s_barrier" ::: "memory");

    for (int t = 0; t < NT; ++t) {
        int buf = t % 3;
        int nbuf = (t + 2) % 3;
        bool pre = (t + 2 < NT);

        // phase 0: issue 3 loads toward tile t+2, then compute kstep 0
        if (pre) { STAGE_A(nbuf, t + 2, 0); STAGE_A(nbuf, t + 2, 1); STAGE_B(nbuf, t + 2, 0); }
        PHASE(buf, 0);
        // phase 1: issue remaining 3 loads, compute kstep 1
        if (pre) { STAGE_A(nbuf, t + 2, 2); STAGE_A(nbuf, t + 2, 3); STAGE_B(nbuf, t + 2, 1); }
        PHASE(buf, 1);

        // tile boundary: wait for tile t+1 only (t+2's 6 loads stay in flight)
        if (t + 1 < NT) {
            if (pre) asm volatile("s_waitcnt vmcnt(6)" ::: "memory");
            else     asm volatile("s_waitcnt vmcnt(0)" ::: "memory");
            asm volatile("s_barrier" ::: "memory");
        }
    }

    // epilogue: C row = 4*rhi + reg (A-side), col = rlo (B-side) — verified layout
    long m0 = (long)blockIdx.x * 256 + wm * 64;
    int n0 = blockIdx.y * 128 + wn * 64;

    if constexpr (MODE == 1) {
        #pragma unroll
        for (int mi = 0; mi < 4; mi++) {
            #pragma unroll
            for (int ni = 0; ni < 4; ni++) {
                int cn = n0 + ni * 16 + rlo;
                #pragma unroll
                for (int r = 0; r < 4; r++) {
                    long rm = m0 + mi * 16 + rhi * 4 + r;
                    Cf[rm * N + cn] = acc[mi][ni][r] + bias[cn];
                }
            }
        }
    } else {
        int type = n0 >> 10;   // 0=q, 1=k, 2=v (per-block uniform: 128 | 1024)
        #pragma unroll
        for (int mi = 0; mi < 4; mi++) {
            long m_ = m0 + mi * 16 + rhi * 4;
            int b = (int)(m_ >> 11);
            int t0 = (int)(m_ & 2047);
            #pragma unroll
            for (int ni = 0; ni < 4; ni++) {
                int n = n0 + ni * 16 + rlo;
                int rem = n & 1023, h = rem >> 6, d = rem & 63;
                long bh = b * 16 + h;
                if (type == 2) {
                    bf16x4 o = { (__bf16)acc[mi][ni][0], (__bf16)acc[mi][ni][1],
                                 (__bf16)acc[mi][ni][2], (__bf16)acc[mi][ni][3] };
                    *reinterpret_cast<bf16x4*>(ovt + (bh * 64 + d) * 2048 + t0) = o;
                } else {
                    __bf16* dst = (type ? ok : oq) + bh * 2048 * 64;
                    #pragma unroll
                    for (int r = 0; r < 4; r++)
                        dst[(long)(t0 + r) * 64 + d] = (__bf16)acc[mi][ni][r];
                }
            }
        }
    }
}

// ---------------------------------------------------------------- attention
// EXACT Round-8 kernel (best measured: 70.5 us) — grid (16, 64); 256 threads
// = 4 waves; fused paired q-tiles {31-p, p}; merged QK^T (shared K-frags);
// SM_PACK -> per-wave Pl; PV from Pl/Vs b128; 2-deep counted-vmcnt pipeline;
// defer-max softmax with lane-local partial l.
__global__ __launch_bounds__(256, 4) void attn_kernel(
    const __bf16* __restrict__ q, const __bf16* __restrict__ k,
    const __bf16* __restrict__ vt, __bf16* __restrict__ attout) {

    __shared__ __bf16 Ks[2][64][64];
    __shared__ __bf16 Vs[2][64][64];
    __shared__ __bf16 Pl[4][16][64];

    int tid = threadIdx.x, lane = tid & 63, wid = tid >> 6;
    int rlo = lane & 15, rhi = lane >> 4;

    int fid = blockIdx.y * 16 + blockIdx.x;
    int xcd = fid & 7, slot = fid >> 3;     // round-robin XCD assumption (perf-only)
    int bh = xcd * 8 + (slot >> 4);         // 8 bh per XCD
    int p = slot & 15;
    int tA = 31 - p, tB = p;                // q-tile indices (64-row tiles)

    int b = bh >> 4, h = bh & 15;
    const __bf16* qb = q + (long)bh * T_ * DH_;
    const __bf16* kb = k + (long)bh * T_ * DH_;
    const __bf16* vtb = vt + (long)bh * T_ * DH_;   // [DH][T]

    const float SCL = 0.125f * 1.44269504088896340736f;  // 1/8 * log2(e)

    // staging geometry (pre-swizzled global source, linear LDS dest)
    int srow = wid * 16 + (lane >> 3);
    int sc0 = (lane & 7) ^ (srow & 7);

    // Q fragments for both tiles (rlo = q row; rhi = d-chunk)
    bf16x8 aqA[2], aqB[2];
    {
        long qrA = (long)tA * 64 + wid * 16 + rlo;
        aqA[0] = *reinterpret_cast<const bf16x8*>(qb + qrA * DH_ + 8 * rhi);
        aqA[1] = *reinterpret_cast<const bf16x8*>(qb + qrA * DH_ + 32 + 8 * rhi);
        long qrB = (long)tB * 64 + wid * 16 + rlo;
        aqB[0] = *reinterpret_cast<const bf16x8*>(qb + qrB * DH_ + 8 * rhi);
        aqB[1] = *reinterpret_cast<const bf16x8*>(qb + qrB * DH_ + 32 + 8 * rhi);
    }

    float mA = NEG_INF, lAc = 0.f, mB = NEG_INF, lBc = 0.f;
    f32x4 oA[4] = {}, oB[4] = {};

    auto STAGE = [&](int bs, int t) {
        const __bf16* ksrc = kb + (long)(t * 64 + srow) * DH_ + sc0 * 8;
        async_copy16(ksrc,           &Ks[bs][wid * 16][0]);
        async_copy16(ksrc + 8 * DH_, &Ks[bs][wid * 16 + 8][0]);
        const __bf16* vsrc = vtb + (long)srow * T_ + t * 64 + sc0 * 8;
        async_copy16(vsrc,           &Vs[bs][wid * 16][0]);
        async_copy16(vsrc + 8 * T_,  &Vs[bs][wid * 16 + 8][0]);
    };

    auto APPLYMASK = [&](f32x4* s, int qrow, int kt0) {
        int kbase = kt0 + rhi * 4;
        #pragma unroll
        for (int f = 0; f < 4; f++)
            #pragma unroll
            for (int r = 0; r < 4; r++)
                if (kbase + f * 16 + r > qrow) s[f][r] = NEG_INF;
    };

    // online softmax on raw s; lane-local partial l; pm reduce only on rescale
    auto SOFTMAX_PV = [&](int bs, f32x4* s, float& m_, float& l_, f32x4* o) {
        f32x4 mx;
        #pragma unroll
        for (int r = 0; r < 4; r++)
            mx[r] = fmaxf(fmaxf(s[0][r], s[1][r]), fmaxf(s[2][r], s[3][r]));
        float pml = fmaxf(fmaxf(mx[0], mx[1]), fmaxf(mx[2], mx[3]));
        float pms = pml * SCL;   // scaled-domain local max

        bool need = !__all(pms <= m_ + 8.f);
        if (need) {
            float pr = fmaxf(pms, __shfl_xor(pms, 16));
            pr = fmaxf(pr, __shfl_xor(pr, 32));
            float nm = fmaxf(m_, pr);
            float so = EXP2F(m_ - nm);
            m_ = nm;
            l_ *= so;
            float sov[4];
            #pragma unroll
            for (int r = 0; r < 4; r++) sov[r] = __shfl(so, rhi * 4 + r);
            #pragma unroll
            for (int fd = 0; fd < 4; fd++)
                #pragma unroll
                for (int r = 0; r < 4; r++)
                    o[fd][r] *= sov[r];
        }

        float rsum = 0.f;
        #pragma unroll
        for (int f = 0; f < 4; f++)
            #pragma unroll
            for (int r = 0; r < 4; r++) {
                float pv = EXP2F(fmaf(s[f][r], SCL, -m_));
                s[f][r] = pv;
                rsum += pv;
            }
        l_ += rsum;   // partial: reduced across rhi groups in epilogue

        // P pack: 4 consecutive keys -> b64 swizzled write
        #pragma unroll
        for (int f = 0; f < 4; f++) {
            bf16x4 pw = { (__bf16)s[f][0], (__bf16)s[f][1],
                          (__bf16)s[f][2], (__bf16)s[f][3] };
            int keyb = f * 16 + rhi * 4;
            int c16 = keyb >> 3, sub = (keyb >> 2) & 1;
            *reinterpret_cast<bf16x4*>(
                &Pl[wid][rlo][((c16 ^ (rlo & 7)) << 3) + (sub << 2)]) = pw;
        }

        // O += P V
        __builtin_amdgcn_s_setprio(1);
        #pragma unroll
        for (int kk = 0; kk < 2; kk++) {
            int ck = kk * 4 + rhi;
            bf16x8 ap = *reinterpret_cast<const bf16x8*>(&Pl[wid][rlo][(ck ^ (rlo & 7)) * 8]);
            #pragma unroll
            for (int fd = 0; fd < 4; fd++) {
                int vr = fd * 16 + rlo;
                bf16x8 bv = *reinterpret_cast<const bf16x8*>(
                    &Vs[bs][vr][(ck ^ (vr & 7)) * 8]);
                o[fd] = __builtin_amdgcn_mfma_f32_16x16x32_bf16(ap, bv, o[fd], 0, 0, 0);
            }
        }
        __builtin_amdgcn_s_setprio(0);
    };

    int qrowA = tA * 64 + wid * 16 + rlo;
    int qrowB = tB * 64 + wid * 16 + rlo;

    int nsteps = tA + 1;   // >= 17

    // prologue: 2-deep prefetch; wait for tile 0 only (vmcnt covers Q loads too)
    STAGE(0, 0);
    STAGE(1, 1);
    asm volatile("s_waitcnt vmcnt(4)" ::: "memory");
    asm volatile("s_barrier" ::: "memory");

    for (int t = 0; t < nsteps; ++t) {
        int cur = t & 1;
        bool doB = (t <= tB);

        // QK^T for both q-tiles, K-fragments read ONCE
        f32x4 sA[4], sB[4];
        __builtin_amdgcn_s_setprio(1);
        #pragma unroll
        for (int f = 0; f < 4; f++) {
            int kr = f * 16 + rlo;
            bf16x8 ak0 = *reinterpret_cast<const bf16x8*>(
                &Ks[cur][kr][((0 + rhi) ^ (kr & 7)) * 8]);
            bf16x8 ak1 = *reinterpret_cast<const bf16x8*>(
                &Ks[cur][kr][((4 + rhi) ^ (kr & 7)) * 8]);
            f32x4 a0 = {};
            a0 = __builtin_amdgcn_mfma_f32_16x16x32_bf16(ak0, aqA[0], a0, 0, 0, 0);
            a0 = __builtin_amdgcn_mfma_f32_16x16x32_bf16(ak1, aqA[1], a0, 0, 0, 0);
            sA[f] = a0;
            if (doB) {
                f32x4 b0 = {};
                b0 = __builtin_amdgcn_mfma_f32_16x16x32_bf16(ak0, aqB[0], b0, 0, 0, 0);
                b0 = __builtin_amdgcn_mfma_f32_16x16x32_bf16(ak1, aqB[1], b0, 0, 0, 0);
                sB[f] = b0;
            }
        }
        __builtin_amdgcn_s_setprio(0);

        if (t == tA) APPLYMASK(sA, qrowA, t * 64);
        SOFTMAX_PV(cur, sA, mA, lAc, oA);
        if (doB) {
            if (t == tB) APPLYMASK(sB, qrowB, t * 64);
            SOFTMAX_PV(cur, sB, mB, lBc, oB);
        }

        // ---- pipeline tail: readers done -> restage freed buffer ->
        // wait only for the OLDEST stage (t+1); t+2's loads stay in flight.
        asm volatile("s_barrier" ::: "memory");
        if (t + 2 < nsteps) {
            STAGE(cur, t + 2);
            asm volatile("s_waitcnt vmcnt(4)" ::: "memory");
        } else {
            asm volatile("s_waitcnt vmcnt(0)" ::: "memory");
        }
        asm volatile("s_barrier" ::: "memory");
    }

    // epilogue: complete the row-sum of l, broadcast, normalize, write
    lAc += __shfl_xor(lAc, 16);
    lAc += __shfl_xor(lAc, 32);
    lBc += __shfl_xor(lBc, 16);
    lBc += __shfl_xor(lBc, 32);

    float lvA[4], lvB[4];
    #pragma unroll
    for (int r = 0; r < 4; r++) {
        lvA[r] = __shfl(lAc, rhi * 4 + r);
        lvB[r] = __shfl(lBc, rhi * 4 + r);
    }
    #pragma unroll
    for (int r = 0; r < 4; r++) {
        float invA = 1.f / lvA[r];
        float invB = 1.f / lvB[r];
        long qrA = (long)tA * 64 + wid * 16 + rhi * 4 + r;
        long qrB = (long)tB * 64 + wid * 16 + rhi * 4 + r;
        #pragma unroll
        for (int fd = 0; fd < 4; fd++) {
            int d = fd * 16 + rlo;
            attout[((long)b * T_ + qrA) * E_ + h * DH_ + d] = (__bf16)(oA[fd][r] * invA);
            attout[((long)b * T_ + qrB) * E_ + h * DH_ + d] = (__bf16)(oB[fd][r] * invB);
        }
    }
}

// ---------------------------------------------------------------- launcher
extern "C" void kernel_launch(void* const* d_in, const int* in_sizes, int n_in,
                              void* d_out, int out_size, void* d_ws, size_t ws_size,
                              hipStream_t stream) {
    const float* x  = (const float*)d_in[0];
    const float* Wq = (const float*)d_in[1];
    const float* Wk = (const float*)d_in[2];
    const float* Wv = (const float*)d_in[3];
    const float* Wp = (const float*)d_in[4];
    const float* bp = (const float*)d_in[5];

    char* ws = (char*)d_ws;
    const long SZ_XE = (long)B_ * T_ * E_ * 2;      // 16 MB (bf16 [B*T][E])
    __bf16* xb   = (__bf16*)(ws);                   // x bf16; REUSED as attout after QKV
    __bf16* qb   = (__bf16*)(ws + SZ_XE);
    __bf16* kb   = (__bf16*)(ws + 2 * SZ_XE);
    __bf16* vt   = (__bf16*)(ws + 3 * SZ_XE);       // V^T: [B*H][DH][T]
    __bf16* wcat = (__bf16*)(ws + 4 * SZ_XE);       // [3072][1024] bf16 (6 MB)
    __bf16* wpb  = (__bf16*)(ws + 4 * SZ_XE + (long)3072 * 1024 * 2);
    __bf16* att  = xb;  // alias: xb dead after QKV GEMM (stream-ordered)

    // fused casts (x, Wp, wcat in one launch)
    cast_all<<<8192, 256, 0, stream>>>(x, Wq, Wk, Wv, Wp, xb, wcat, wpb);

    // fused QKV projection: [8192][1024] @ wcat^T -> q/k [bh][t][d], vt [bh][d][t]
    // 768 blocks = 3 full CU-rounds, no tail
    gemm256<3><<<dim3(32, 24), 512, 0, stream>>>(
        xb, wcat, nullptr, nullptr, qb, kb, vt, E_, 3 * E_);

    // causal attention (exact R8 kernel — best measured)
    attn_kernel<<<dim3(16, B_ * H_), 256, 0, stream>>>(qb, kb, vt, att);

    // output projection + bias (fp32 out): 256 blocks = 1 full CU-round
    gemm256<1><<<dim3(32, 8), 512, 0, stream>>>(
        att, wpb, (float*)d_out, bp, nullptr, nullptr, nullptr, E_, E_);
}

// Round 14
// 163.092 us; speedup vs baseline: 1.1674x; 1.1674x over previous
//
#include <hip/hip_runtime.h>
#include <hip/hip_bf16.h>

// Problem constants
#define B_ 4
#define T_ 2048
#define E_ 1024
#define H_ 16
#define DH_ 64

typedef __bf16 bf16x8 __attribute__((ext_vector_type(8)));
typedef __bf16 bf16x4 __attribute__((ext_vector_type(4)));
typedef float f32x4 __attribute__((ext_vector_type(4)));

#define EXP2F(x) __builtin_amdgcn_exp2f(x)
#define NEG_INF (-__builtin_inff())

// async global->LDS, 16B per lane: lane l writes lds_base + l*16
__device__ __forceinline__ void async_copy16(const __bf16* g, __bf16* l) {
    __builtin_amdgcn_global_load_lds(
        (const __attribute__((address_space(1))) unsigned int*)g,
        (__attribute__((address_space(3))) unsigned int*)l, 16, 0, 0);
}

// ---------------------------------------------------------------- fused casts
__global__ void cast_all(const float* __restrict__ x,
                         const float* __restrict__ Wq, const float* __restrict__ Wk,
                         const float* __restrict__ Wv, const float* __restrict__ Wp,
                         __bf16* __restrict__ xb, __bf16* __restrict__ wcat,
                         __bf16* __restrict__ wpb) {
    int tid = blockIdx.x * blockDim.x + threadIdx.x;   // grid covers 2,097,152
    {
        int i = tid * 4;                                // x: B*T*E = 8,388,608
        float4 f = *reinterpret_cast<const float4*>(x + i);
        bf16x4 o = { (__bf16)f.x, (__bf16)f.y, (__bf16)f.z, (__bf16)f.w };
        *reinterpret_cast<bf16x4*>(xb + i) = o;
    }
    if (tid < 262144) {                                 // Wp: 1,048,576
        int i = tid * 4;
        float4 f = *reinterpret_cast<const float4*>(Wp + i);
        bf16x4 o = { (__bf16)f.x, (__bf16)f.y, (__bf16)f.z, (__bf16)f.w };
        *reinterpret_cast<bf16x4*>(wpb + i) = o;
    }
    if (tid < 786432) {                                 // wcat: 3072*1024
        int i = tid * 4;
        int e = i & (E_ - 1);                           // 4 consecutive e
        int n = i >> 10;
        int rem = n & 1023, h = rem >> 6, d = rem & 63;
        const float* src = (n < 1024) ? Wq : (n < 2048 ? Wk : Wv);
        const float* sp = src + ((long)((h << 10) + e)) * DH_ + d;
        bf16x4 o = { (__bf16)sp[0], (__bf16)sp[DH_], (__bf16)sp[2 * DH_], (__bf16)sp[3 * DH_] };
        *reinterpret_cast<bf16x4*>(wcat + i) = o;
    }
}

// ---------------------------------------------------------------- GEMM (C = A * Bt^T)
// 128x128 tile, BK=64, 4 waves (2x2), global_load_lds staging (pre-swizzled src).
// 1-D grid + XCD-chunked block remap: each XCD owns a contiguous chunk of
// A-row-blocks and cycles N fastest -> per-XCD L2 resident set = its A-panels
// + all B-panels (L2-fits), cutting L3/HBM A re-reads.
// MODE 1: C[m][N] f32 + bias.   MODE 3: QKV epilogue -> q/k [bh][t][d], vt [bh][d][t].
template<int MODE>
__global__ __launch_bounds__(256, 3) void gemm128(
    const __bf16* __restrict__ A, const __bf16* __restrict__ Bt,
    float* __restrict__ Cf, const float* __restrict__ bias,
    __bf16* __restrict__ oq, __bf16* __restrict__ ok, __bf16* __restrict__ ovt,
    int K, int N) {

    __shared__ __bf16 As[128][64];
    __shared__ __bf16 Bs[128][64];

    int tid = threadIdx.x, lane = tid & 63, wid = tid >> 6;
    int wr = wid >> 1, wc = wid & 1;
    int rlo = lane & 15, rhi = lane >> 4;
    int l8 = lane >> 3, c = lane & 7;

    // XCD-chunked remap (bijective: gridDim.x % 8 == 0)
    int nY = N >> 7;                      // N-blocks (24 QKV / 8 proj)
    int chunk = (int)gridDim.x / (8 * nY);
    int fid = blockIdx.x;
    int xcd = fid & 7, slot = fid >> 3;   // round-robin XCD dispatch (perf-only)
    int bx = xcd * chunk + slot / nY;
    int by = slot % nY;

    const __bf16* Ab = A + (long)bx * 128 * K;
    const __bf16* Bb = Bt + (long)by * 128 * K;

    f32x4 acc[4][4] = {};

    for (int k0 = 0; k0 < K; k0 += 64) {
        #pragma unroll
        for (int p = 0; p < 4; p++) {
            int gr = p * 32 + wid * 8 + l8;
            int sc = c ^ (gr & 7);
            async_copy16(Ab + (long)gr * K + k0 + sc * 8, &As[p * 32 + wid * 8][0]);
        }
        #pragma unroll
        for (int p = 0; p < 4; p++) {
            int gr = p * 32 + wid * 8 + l8;
            int sc = c ^ (gr & 7);
            async_copy16(Bb + (long)gr * K + k0 + sc * 8, &Bs[p * 32 + wid * 8][0]);
        }
        __syncthreads();   // drains vmcnt -> tiles ready

        #pragma unroll
        for (int kk = 0; kk < 2; kk++) {
            bf16x8 af[4], bfr[4];
            #pragma unroll
            for (int mi = 0; mi < 4; mi++) {
                int r = wr * 64 + mi * 16 + rlo;
                af[mi] = *reinterpret_cast<const bf16x8*>(
                    &As[r][((kk * 4 + rhi) ^ (r & 7)) * 8]);
            }
            #pragma unroll
            for (int ni = 0; ni < 4; ni++) {
                int r = wc * 64 + ni * 16 + rlo;
                bfr[ni] = *reinterpret_cast<const bf16x8*>(
                    &Bs[r][((kk * 4 + rhi) ^ (r & 7)) * 8]);
            }
            #pragma unroll
            for (int mi = 0; mi < 4; mi++)
                #pragma unroll
                for (int ni = 0; ni < 4; ni++)
                    acc[mi][ni] = __builtin_amdgcn_mfma_f32_16x16x32_bf16(
                        af[mi], bfr[ni], acc[mi][ni], 0, 0, 0);
        }
        __syncthreads();   // WAR before next stage
    }

    long m0 = (long)bx * 128 + wr * 64;
    int n0 = by * 128 + wc * 64;

    if constexpr (MODE == 1) {
        #pragma unroll
        for (int mi = 0; mi < 4; mi++) {
            #pragma unroll
            for (int ni = 0; ni < 4; ni++) {
                int cn = n0 + ni * 16 + rlo;
                #pragma unroll
                for (int r = 0; r < 4; r++) {
                    long rm = m0 + mi * 16 + rhi * 4 + r;
                    Cf[rm * N + cn] = acc[mi][ni][r] + bias[cn];
                }
            }
        }
    } else {
        int type = by >> 3;   // 0=q, 1=k, 2=v (N=3072, 8 n-blocks each)
        #pragma unroll
        for (int mi = 0; mi < 4; mi++) {
            long m_ = m0 + mi * 16 + rhi * 4;
            int b = (int)(m_ >> 11);
            int t0 = (int)(m_ & 2047);
            #pragma unroll
            for (int ni = 0; ni < 4; ni++) {
                int n = n0 + ni * 16 + rlo;
                int rem = n & 1023, h = rem >> 6, d = rem & 63;
                long bh = b * 16 + h;
                if (type == 2) {
                    bf16x4 o = { (__bf16)acc[mi][ni][0], (__bf16)acc[mi][ni][1],
                                 (__bf16)acc[mi][ni][2], (__bf16)acc[mi][ni][3] };
                    *reinterpret_cast<bf16x4*>(ovt + (bh * 64 + d) * 2048 + t0) = o;
                } else {
                    __bf16* dst = (type ? ok : oq) + bh * 2048 * 64;
                    #pragma unroll
                    for (int r = 0; r < 4; r++)
                        dst[(long)(t0 + r) * 64 + d] = (__bf16)acc[mi][ni][r];
                }
            }
        }
    }
}

// ---------------------------------------------------------------- attention
// EXACT Round-8 kernel (best measured: 70.5 us) — grid (16, 64); 256 threads
// = 4 waves; fused paired q-tiles {31-p, p}; merged QK^T (shared K-frags);
// SM_PACK -> per-wave Pl; PV from Pl/Vs b128; 2-deep counted-vmcnt pipeline;
// defer-max softmax with lane-local partial l.
__global__ __launch_bounds__(256, 4) void attn_kernel(
    const __bf16* __restrict__ q, const __bf16* __restrict__ k,
    const __bf16* __restrict__ vt, __bf16* __restrict__ attout) {

    __shared__ __bf16 Ks[2][64][64];
    __shared__ __bf16 Vs[2][64][64];
    __shared__ __bf16 Pl[4][16][64];

    int tid = threadIdx.x, lane = tid & 63, wid = tid >> 6;
    int rlo = lane & 15, rhi = lane >> 4;

    int fid = blockIdx.y * 16 + blockIdx.x;
    int xcd = fid & 7, slot = fid >> 3;     // round-robin XCD assumption (perf-only)
    int bh = xcd * 8 + (slot >> 4);         // 8 bh per XCD
    int p = slot & 15;
    int tA = 31 - p, tB = p;                // q-tile indices (64-row tiles)

    int b = bh >> 4, h = bh & 15;
    const __bf16* qb = q + (long)bh * T_ * DH_;
    const __bf16* kb = k + (long)bh * T_ * DH_;
    const __bf16* vtb = vt + (long)bh * T_ * DH_;   // [DH][T]

    const float SCL = 0.125f * 1.44269504088896340736f;  // 1/8 * log2(e)

    // staging geometry (pre-swizzled global source, linear LDS dest)
    int srow = wid * 16 + (lane >> 3);
    int sc0 = (lane & 7) ^ (srow & 7);

    // Q fragments for both tiles (rlo = q row; rhi = d-chunk)
    bf16x8 aqA[2], aqB[2];
    {
        long qrA = (long)tA * 64 + wid * 16 + rlo;
        aqA[0] = *reinterpret_cast<const bf16x8*>(qb + qrA * DH_ + 8 * rhi);
        aqA[1] = *reinterpret_cast<const bf16x8*>(qb + qrA * DH_ + 32 + 8 * rhi);
        long qrB = (long)tB * 64 + wid * 16 + rlo;
        aqB[0] = *reinterpret_cast<const bf16x8*>(qb + qrB * DH_ + 8 * rhi);
        aqB[1] = *reinterpret_cast<const bf16x8*>(qb + qrB * DH_ + 32 + 8 * rhi);
    }

    float mA = NEG_INF, lAc = 0.f, mB = NEG_INF, lBc = 0.f;
    f32x4 oA[4] = {}, oB[4] = {};

    auto STAGE = [&](int bs, int t) {
        const __bf16* ksrc = kb + (long)(t * 64 + srow) * DH_ + sc0 * 8;
        async_copy16(ksrc,           &Ks[bs][wid * 16][0]);
        async_copy16(ksrc + 8 * DH_, &Ks[bs][wid * 16 + 8][0]);
        const __bf16* vsrc = vtb + (long)srow * T_ + t * 64 + sc0 * 8;
        async_copy16(vsrc,           &Vs[bs][wid * 16][0]);
        async_copy16(vsrc + 8 * T_,  &Vs[bs][wid * 16 + 8][0]);
    };

    auto APPLYMASK = [&](f32x4* s, int qrow, int kt0) {
        int kbase = kt0 + rhi * 4;
        #pragma unroll
        for (int f = 0; f < 4; f++)
            #pragma unroll
            for (int r = 0; r < 4; r++)
                if (kbase + f * 16 + r > qrow) s[f][r] = NEG_INF;
    };

    // online softmax on raw s; lane-local partial l; pm reduce only on rescale
    auto SOFTMAX_PV = [&](int bs, f32x4* s, float& m_, float& l_, f32x4* o) {
        f32x4 mx;
        #pragma unroll
        for (int r = 0; r < 4; r++)
            mx[r] = fmaxf(fmaxf(s[0][r], s[1][r]), fmaxf(s[2][r], s[3][r]));
        float pml = fmaxf(fmaxf(mx[0], mx[1]), fmaxf(mx[2], mx[3]));
        float pms = pml * SCL;   // scaled-domain local max

        bool need = !__all(pms <= m_ + 8.f);
        if (need) {
            float pr = fmaxf(pms, __shfl_xor(pms, 16));
            pr = fmaxf(pr, __shfl_xor(pr, 32));
            float nm = fmaxf(m_, pr);
            float so = EXP2F(m_ - nm);
            m_ = nm;
            l_ *= so;
            float sov[4];
            #pragma unroll
            for (int r = 0; r < 4; r++) sov[r] = __shfl(so, rhi * 4 + r);
            #pragma unroll
            for (int fd = 0; fd < 4; fd++)
                #pragma unroll
                for (int r = 0; r < 4; r++)
                    o[fd][r] *= sov[r];
        }

        float rsum = 0.f;
        #pragma unroll
        for (int f = 0; f < 4; f++)
            #pragma unroll
            for (int r = 0; r < 4; r++) {
                float pv = EXP2F(fmaf(s[f][r], SCL, -m_));
                s[f][r] = pv;
                rsum += pv;
            }
        l_ += rsum;   // partial: reduced across rhi groups in epilogue

        // P pack: 4 consecutive keys -> b64 swizzled write
        #pragma unroll
        for (int f = 0; f < 4; f++) {
            bf16x4 pw = { (__bf16)s[f][0], (__bf16)s[f][1],
                          (__bf16)s[f][2], (__bf16)s[f][3] };
            int keyb = f * 16 + rhi * 4;
            int c16 = keyb >> 3, sub = (keyb >> 2) & 1;
            *reinterpret_cast<bf16x4*>(
                &Pl[wid][rlo][((c16 ^ (rlo & 7)) << 3) + (sub << 2)]) = pw;
        }

        // O += P V
        __builtin_amdgcn_s_setprio(1);
        #pragma unroll
        for (int kk = 0; kk < 2; kk++) {
            int ck = kk * 4 + rhi;
            bf16x8 ap = *reinterpret_cast<const bf16x8*>(&Pl[wid][rlo][(ck ^ (rlo & 7)) * 8]);
            #pragma unroll
            for (int fd = 0; fd < 4; fd++) {
                int vr = fd * 16 + rlo;
                bf16x8 bv = *reinterpret_cast<const bf16x8*>(
                    &Vs[bs][vr][(ck ^ (vr & 7)) * 8]);
                o[fd] = __builtin_amdgcn_mfma_f32_16x16x32_bf16(ap, bv, o[fd], 0, 0, 0);
            }
        }
        __builtin_amdgcn_s_setprio(0);
    };

    int qrowA = tA * 64 + wid * 16 + rlo;
    int qrowB = tB * 64 + wid * 16 + rlo;

    int nsteps = tA + 1;   // >= 17

    // prologue: 2-deep prefetch; wait for tile 0 only (vmcnt covers Q loads too)
    STAGE(0, 0);
    STAGE(1, 1);
    asm volatile("s_waitcnt vmcnt(4)" ::: "memory");
    asm volatile("s_barrier" ::: "memory");

    for (int t = 0; t < nsteps; ++t) {
        int cur = t & 1;
        bool doB = (t <= tB);

        // QK^T for both q-tiles, K-fragments read ONCE
        f32x4 sA[4], sB[4];
        __builtin_amdgcn_s_setprio(1);
        #pragma unroll
        for (int f = 0; f < 4; f++) {
            int kr = f * 16 + rlo;
            bf16x8 ak0 = *reinterpret_cast<const bf16x8*>(
                &Ks[cur][kr][((0 + rhi) ^ (kr & 7)) * 8]);
            bf16x8 ak1 = *reinterpret_cast<const bf16x8*>(
                &Ks[cur][kr][((4 + rhi) ^ (kr & 7)) * 8]);
            f32x4 a0 = {};
            a0 = __builtin_amdgcn_mfma_f32_16x16x32_bf16(ak0, aqA[0], a0, 0, 0, 0);
            a0 = __builtin_amdgcn_mfma_f32_16x16x32_bf16(ak1, aqA[1], a0, 0, 0, 0);
            sA[f] = a0;
            if (doB) {
                f32x4 b0 = {};
                b0 = __builtin_amdgcn_mfma_f32_16x16x32_bf16(ak0, aqB[0], b0, 0, 0, 0);
                b0 = __builtin_amdgcn_mfma_f32_16x16x32_bf16(ak1, aqB[1], b0, 0, 0, 0);
                sB[f] = b0;
            }
        }
        __builtin_amdgcn_s_setprio(0);

        if (t == tA) APPLYMASK(sA, qrowA, t * 64);
        SOFTMAX_PV(cur, sA, mA, lAc, oA);
        if (doB) {
            if (t == tB) APPLYMASK(sB, qrowB, t * 64);
            SOFTMAX_PV(cur, sB, mB, lBc, oB);
        }

        // ---- pipeline tail: readers done -> restage freed buffer ->
        // wait only for the OLDEST stage (t+1); t+2's loads stay in flight.
        asm volatile("s_barrier" ::: "memory");
        if (t + 2 < nsteps) {
            STAGE(cur, t + 2);
            asm volatile("s_waitcnt vmcnt(4)" ::: "memory");
        } else {
            asm volatile("s_waitcnt vmcnt(0)" ::: "memory");
        }
        asm volatile("s_barrier" ::: "memory");
    }

    // epilogue: complete the row-sum of l, broadcast, normalize, write
    lAc += __shfl_xor(lAc, 16);
    lAc += __shfl_xor(lAc, 32);
    lBc += __shfl_xor(lBc, 16);
    lBc += __shfl_xor(lBc, 32);

    float lvA[4], lvB[4];
    #pragma unroll
    for (int r = 0; r < 4; r++) {
        lvA[r] = __shfl(lAc, rhi * 4 + r);
        lvB[r] = __shfl(lBc, rhi * 4 + r);
    }
    #pragma unroll
    for (int r = 0; r < 4; r++) {
        float invA = 1.f / lvA[r];
        float invB = 1.f / lvB[r];
        long qrA = (long)tA * 64 + wid * 16 + rhi * 4 + r;
        long qrB = (long)tB * 64 + wid * 16 + rhi * 4 + r;
        #pragma unroll
        for (int fd = 0; fd < 4; fd++) {
            int d = fd * 16 + rlo;
            attout[((long)b * T_ + qrA) * E_ + h * DH_ + d] = (__bf16)(oA[fd][r] * invA);
            attout[((long)b * T_ + qrB) * E_ + h * DH_ + d] = (__bf16)(oB[fd][r] * invB);
        }
    }
}

// ---------------------------------------------------------------- launcher
extern "C" void kernel_launch(void* const* d_in, const int* in_sizes, int n_in,
                              void* d_out, int out_size, void* d_ws, size_t ws_size,
                              hipStream_t stream) {
    const float* x  = (const float*)d_in[0];
    const float* Wq = (const float*)d_in[1];
    const float* Wk = (const float*)d_in[2];
    const float* Wv = (const float*)d_in[3];
    const float* Wp = (const float*)d_in[4];
    const float* bp = (const float*)d_in[5];

    char* ws = (char*)d_ws;
    const long SZ_XE = (long)B_ * T_ * E_ * 2;      // 16 MB (bf16 [B*T][E])
    __bf16* xb   = (__bf16*)(ws);                   // x bf16; REUSED as attout after QKV
    __bf16* qb   = (__bf16*)(ws + SZ_XE);
    __bf16* kb   = (__bf16*)(ws + 2 * SZ_XE);
    __bf16* vt   = (__bf16*)(ws + 3 * SZ_XE);       // V^T: [B*H][DH][T]
    __bf16* wcat = (__bf16*)(ws + 4 * SZ_XE);       // [3072][1024] bf16 (6 MB)
    __bf16* wpb  = (__bf16*)(ws + 4 * SZ_XE + (long)3072 * 1024 * 2);
    __bf16* att  = xb;  // alias: xb dead after QKV GEMM (stream-ordered)

    // fused casts (x, Wp, wcat in one launch)
    cast_all<<<8192, 256, 0, stream>>>(x, Wq, Wk, Wv, Wp, xb, wcat, wpb);

    // fused QKV projection: [8192][1024] @ wcat^T -> q/k [bh][t][d], vt [bh][d][t]
    // 1536 blocks, XCD-chunked remap inside
    gemm128<3><<<1536, 256, 0, stream>>>(
        xb, wcat, nullptr, nullptr, qb, kb, vt, E_, 3 * E_);

    // causal attention (exact R8 kernel — best measured)
    attn_kernel<<<dim3(16, B_ * H_), 256, 0, stream>>>(qb, kb, vt, att);

    // output projection + bias (fp32 out): 512 blocks, XCD-chunked remap inside
    gemm128<1><<<512, 256, 0, stream>>>(
        att, wpb, (float*)d_out, bp, nullptr, nullptr, nullptr, E_, E_);
}

// Round 15
// 158.760 us; speedup vs baseline: 1.1993x; 1.0273x over previous
//
#include <hip/hip_runtime.h>
#include <hip/hip_bf16.h>

// Problem constants
#define B_ 4
#define T_ 2048
#define E_ 1024
#define H_ 16
#define DH_ 64

typedef __bf16 bf16x8 __attribute__((ext_vector_type(8)));
typedef __bf16 bf16x4 __attribute__((ext_vector_type(4)));
typedef float f32x4 __attribute__((ext_vector_type(4)));

#define EXP2F(x) __builtin_amdgcn_exp2f(x)
#define NEG_INF (-__builtin_inff())

// async global->LDS, 16B per lane: lane l writes lds_base + l*16
__device__ __forceinline__ void async_copy16(const __bf16* g, __bf16* l) {
    __builtin_amdgcn_global_load_lds(
        (const __attribute__((address_space(1))) unsigned int*)g,
        (__attribute__((address_space(3))) unsigned int*)l, 16, 0, 0);
}

// ---------------------------------------------------------------- fused casts
// one launch: x (8.4M), Wp (1M), wcat build (3.1M) — all bf16x4 stores
__global__ void cast_all(const float* __restrict__ x,
                         const float* __restrict__ Wq, const float* __restrict__ Wk,
                         const float* __restrict__ Wv, const float* __restrict__ Wp,
                         __bf16* __restrict__ xb, __bf16* __restrict__ wcat,
                         __bf16* __restrict__ wpb) {
    int tid = blockIdx.x * blockDim.x + threadIdx.x;   // grid covers 2,097,152
    {
        int i = tid * 4;                                // x: B*T*E = 8,388,608
        float4 f = *reinterpret_cast<const float4*>(x + i);
        bf16x4 o = { (__bf16)f.x, (__bf16)f.y, (__bf16)f.z, (__bf16)f.w };
        *reinterpret_cast<bf16x4*>(xb + i) = o;
    }
    if (tid < 262144) {                                 // Wp: 1,048,576
        int i = tid * 4;
        float4 f = *reinterpret_cast<const float4*>(Wp + i);
        bf16x4 o = { (__bf16)f.x, (__bf16)f.y, (__bf16)f.z, (__bf16)f.w };
        *reinterpret_cast<bf16x4*>(wpb + i) = o;
    }
    if (tid < 786432) {                                 // wcat: 3072*1024
        int i = tid * 4;
        int e = i & (E_ - 1);                           // 4 consecutive e
        int n = i >> 10;
        int rem = n & 1023, h = rem >> 6, d = rem & 63;
        const float* src = (n < 1024) ? Wq : (n < 2048 ? Wk : Wv);
        const float* sp = src + ((long)((h << 10) + e)) * DH_ + d;
        bf16x4 o = { (__bf16)sp[0], (__bf16)sp[DH_], (__bf16)sp[2 * DH_], (__bf16)sp[3 * DH_] };
        *reinterpret_cast<bf16x4*>(wcat + i) = o;
    }
}

// ---------------------------------------------------------------- GEMM v2 (C = A * Bt^T)
// 128x128 tile, BK=64, 4 waves (2x2), global_load_lds staging (pre-swizzled src).
// MODE 1: C[m][N] f32 + bias.   MODE 3: QKV epilogue -> q/k [bh][t][d], vt [bh][d][t].
template<int MODE>
__global__ __launch_bounds__(256, 3) void gemm128(
    const __bf16* __restrict__ A, const __bf16* __restrict__ Bt,
    float* __restrict__ Cf, const float* __restrict__ bias,
    __bf16* __restrict__ oq, __bf16* __restrict__ ok, __bf16* __restrict__ ovt,
    int K, int N) {

    __shared__ __bf16 As[128][64];
    __shared__ __bf16 Bs[128][64];

    int tid = threadIdx.x, lane = tid & 63, wid = tid >> 6;
    int wr = wid >> 1, wc = wid & 1;
    int rlo = lane & 15, rhi = lane >> 4;
    int l8 = lane >> 3, c = lane & 7;

    const __bf16* Ab = A + (long)blockIdx.x * 128 * K;
    const __bf16* Bb = Bt + (long)blockIdx.y * 128 * K;

    f32x4 acc[4][4] = {};

    for (int k0 = 0; k0 < K; k0 += 64) {
        #pragma unroll
        for (int p = 0; p < 4; p++) {
            int gr = p * 32 + wid * 8 + l8;
            int sc = c ^ (gr & 7);
            async_copy16(Ab + (long)gr * K + k0 + sc * 8, &As[p * 32 + wid * 8][0]);
        }
        #pragma unroll
        for (int p = 0; p < 4; p++) {
            int gr = p * 32 + wid * 8 + l8;
            int sc = c ^ (gr & 7);
            async_copy16(Bb + (long)gr * K + k0 + sc * 8, &Bs[p * 32 + wid * 8][0]);
        }
        __syncthreads();   // drains vmcnt -> tiles ready

        #pragma unroll
        for (int kk = 0; kk < 2; kk++) {
            bf16x8 af[4], bfr[4];
            #pragma unroll
            for (int mi = 0; mi < 4; mi++) {
                int r = wr * 64 + mi * 16 + rlo;
                af[mi] = *reinterpret_cast<const bf16x8*>(
                    &As[r][((kk * 4 + rhi) ^ (r & 7)) * 8]);
            }
            #pragma unroll
            for (int ni = 0; ni < 4; ni++) {
                int r = wc * 64 + ni * 16 + rlo;
                bfr[ni] = *reinterpret_cast<const bf16x8*>(
                    &Bs[r][((kk * 4 + rhi) ^ (r & 7)) * 8]);
            }
            #pragma unroll
            for (int mi = 0; mi < 4; mi++)
                #pragma unroll
                for (int ni = 0; ni < 4; ni++)
                    acc[mi][ni] = __builtin_amdgcn_mfma_f32_16x16x32_bf16(
                        af[mi], bfr[ni], acc[mi][ni], 0, 0, 0);
        }
        __syncthreads();   // WAR before next stage
    }

    long m0 = (long)blockIdx.x * 128 + wr * 64;
    int n0 = blockIdx.y * 128 + wc * 64;

    if constexpr (MODE == 1) {
        #pragma unroll
        for (int mi = 0; mi < 4; mi++) {
            #pragma unroll
            for (int ni = 0; ni < 4; ni++) {
                int cn = n0 + ni * 16 + rlo;
                #pragma unroll
                for (int r = 0; r < 4; r++) {
                    long rm = m0 + mi * 16 + rhi * 4 + r;
                    Cf[rm * N + cn] = acc[mi][ni][r] + bias[cn];
                }
            }
        }
    } else {
        int type = blockIdx.y >> 3;   // 0=q, 1=k, 2=v (N=3072, 8 n-blocks each)
        #pragma unroll
        for (int mi = 0; mi < 4; mi++) {
            long m_ = m0 + mi * 16 + rhi * 4;
            int b = (int)(m_ >> 11);
            int t0 = (int)(m_ & 2047);
            #pragma unroll
            for (int ni = 0; ni < 4; ni++) {
                int n = n0 + ni * 16 + rlo;
                int rem = n & 1023, h = rem >> 6, d = rem & 63;
                long bh = b * 16 + h;
                if (type == 2) {
                    bf16x4 o = { (__bf16)acc[mi][ni][0], (__bf16)acc[mi][ni][1],
                                 (__bf16)acc[mi][ni][2], (__bf16)acc[mi][ni][3] };
                    *reinterpret_cast<bf16x4*>(ovt + (bh * 64 + d) * 2048 + t0) = o;
                } else {
                    __bf16* dst = (type ? ok : oq) + bh * 2048 * 64;
                    #pragma unroll
                    for (int r = 0; r < 4; r++)
                        dst[(long)(t0 + r) * 64 + d] = (__bf16)acc[mi][ni][r];
                }
            }
        }
    }
}

// ---------------------------------------------------------------- attention
// EXACT Round-8 kernel (best measured: 70.5 us) — grid (16, 64); 256 threads
// = 4 waves; fused paired q-tiles {31-p, p}; merged QK^T (shared K-frags);
// SM_PACK -> per-wave Pl; PV from Pl/Vs b128; 2-deep counted-vmcnt pipeline;
// defer-max softmax with lane-local partial l.
__global__ __launch_bounds__(256, 4) void attn_kernel(
    const __bf16* __restrict__ q, const __bf16* __restrict__ k,
    const __bf16* __restrict__ vt, __bf16* __restrict__ attout) {

    __shared__ __bf16 Ks[2][64][64];
    __shared__ __bf16 Vs[2][64][64];
    __shared__ __bf16 Pl[4][16][64];

    int tid = threadIdx.x, lane = tid & 63, wid = tid >> 6;
    int rlo = lane & 15, rhi = lane >> 4;

    int fid = blockIdx.y * 16 + blockIdx.x;
    int xcd = fid & 7, slot = fid >> 3;     // round-robin XCD assumption (perf-only)
    int bh = xcd * 8 + (slot >> 4);         // 8 bh per XCD
    int p = slot & 15;
    int tA = 31 - p, tB = p;                // q-tile indices (64-row tiles)

    int b = bh >> 4, h = bh & 15;
    const __bf16* qb = q + (long)bh * T_ * DH_;
    const __bf16* kb = k + (long)bh * T_ * DH_;
    const __bf16* vtb = vt + (long)bh * T_ * DH_;   // [DH][T]

    const float SCL = 0.125f * 1.44269504088896340736f;  // 1/8 * log2(e)

    // staging geometry (pre-swizzled global source, linear LDS dest)
    int srow = wid * 16 + (lane >> 3);
    int sc0 = (lane & 7) ^ (srow & 7);

    // Q fragments for both tiles (rlo = q row; rhi = d-chunk)
    bf16x8 aqA[2], aqB[2];
    {
        long qrA = (long)tA * 64 + wid * 16 + rlo;
        aqA[0] = *reinterpret_cast<const bf16x8*>(qb + qrA * DH_ + 8 * rhi);
        aqA[1] = *reinterpret_cast<const bf16x8*>(qb + qrA * DH_ + 32 + 8 * rhi);
        long qrB = (long)tB * 64 + wid * 16 + rlo;
        aqB[0] = *reinterpret_cast<const bf16x8*>(qb + qrB * DH_ + 8 * rhi);
        aqB[1] = *reinterpret_cast<const bf16x8*>(qb + qrB * DH_ + 32 + 8 * rhi);
    }

    float mA = NEG_INF, lAc = 0.f, mB = NEG_INF, lBc = 0.f;
    f32x4 oA[4] = {}, oB[4] = {};

    auto STAGE = [&](int bs, int t) {
        const __bf16* ksrc = kb + (long)(t * 64 + srow) * DH_ + sc0 * 8;
        async_copy16(ksrc,           &Ks[bs][wid * 16][0]);
        async_copy16(ksrc + 8 * DH_, &Ks[bs][wid * 16 + 8][0]);
        const __bf16* vsrc = vtb + (long)srow * T_ + t * 64 + sc0 * 8;
        async_copy16(vsrc,           &Vs[bs][wid * 16][0]);
        async_copy16(vsrc + 8 * T_,  &Vs[bs][wid * 16 + 8][0]);
    };

    auto APPLYMASK = [&](f32x4* s, int qrow, int kt0) {
        int kbase = kt0 + rhi * 4;
        #pragma unroll
        for (int f = 0; f < 4; f++)
            #pragma unroll
            for (int r = 0; r < 4; r++)
                if (kbase + f * 16 + r > qrow) s[f][r] = NEG_INF;
    };

    // online softmax on raw s; lane-local partial l; pm reduce only on rescale
    auto SOFTMAX_PV = [&](int bs, f32x4* s, float& m_, float& l_, f32x4* o) {
        f32x4 mx;
        #pragma unroll
        for (int r = 0; r < 4; r++)
            mx[r] = fmaxf(fmaxf(s[0][r], s[1][r]), fmaxf(s[2][r], s[3][r]));
        float pml = fmaxf(fmaxf(mx[0], mx[1]), fmaxf(mx[2], mx[3]));
        float pms = pml * SCL;   // scaled-domain local max

        bool need = !__all(pms <= m_ + 8.f);
        if (need) {
            float pr = fmaxf(pms, __shfl_xor(pms, 16));
            pr = fmaxf(pr, __shfl_xor(pr, 32));
            float nm = fmaxf(m_, pr);
            float so = EXP2F(m_ - nm);
            m_ = nm;
            l_ *= so;
            float sov[4];
            #pragma unroll
            for (int r = 0; r < 4; r++) sov[r] = __shfl(so, rhi * 4 + r);
            #pragma unroll
            for (int fd = 0; fd < 4; fd++)
                #pragma unroll
                for (int r = 0; r < 4; r++)
                    o[fd][r] *= sov[r];
        }

        float rsum = 0.f;
        #pragma unroll
        for (int f = 0; f < 4; f++)
            #pragma unroll
            for (int r = 0; r < 4; r++) {
                float pv = EXP2F(fmaf(s[f][r], SCL, -m_));
                s[f][r] = pv;
                rsum += pv;
            }
        l_ += rsum;   // partial: reduced across rhi groups in epilogue

        // P pack: 4 consecutive keys -> b64 swizzled write
        #pragma unroll
        for (int f = 0; f < 4; f++) {
            bf16x4 pw = { (__bf16)s[f][0], (__bf16)s[f][1],
                          (__bf16)s[f][2], (__bf16)s[f][3] };
            int keyb = f * 16 + rhi * 4;
            int c16 = keyb >> 3, sub = (keyb >> 2) & 1;
            *reinterpret_cast<bf16x4*>(
                &Pl[wid][rlo][((c16 ^ (rlo & 7)) << 3) + (sub << 2)]) = pw;
        }

        // O += P V
        __builtin_amdgcn_s_setprio(1);
        #pragma unroll
        for (int kk = 0; kk < 2; kk++) {
            int ck = kk * 4 + rhi;
            bf16x8 ap = *reinterpret_cast<const bf16x8*>(&Pl[wid][rlo][(ck ^ (rlo & 7)) * 8]);
            #pragma unroll
            for (int fd = 0; fd < 4; fd++) {
                int vr = fd * 16 + rlo;
                bf16x8 bv = *reinterpret_cast<const bf16x8*>(
                    &Vs[bs][vr][(ck ^ (vr & 7)) * 8]);
                o[fd] = __builtin_amdgcn_mfma_f32_16x16x32_bf16(ap, bv, o[fd], 0, 0, 0);
            }
        }
        __builtin_amdgcn_s_setprio(0);
    };

    int qrowA = tA * 64 + wid * 16 + rlo;
    int qrowB = tB * 64 + wid * 16 + rlo;

    int nsteps = tA + 1;   // >= 17

    // prologue: 2-deep prefetch; wait for tile 0 only (vmcnt covers Q loads too)
    STAGE(0, 0);
    STAGE(1, 1);
    asm volatile("s_waitcnt vmcnt(4)" ::: "memory");
    asm volatile("s_barrier" ::: "memory");

    for (int t = 0; t < nsteps; ++t) {
        int cur = t & 1;
        bool doB = (t <= tB);

        // QK^T for both q-tiles, K-fragments read ONCE
        f32x4 sA[4], sB[4];
        __builtin_amdgcn_s_setprio(1);
        #pragma unroll
        for (int f = 0; f < 4; f++) {
            int kr = f * 16 + rlo;
            bf16x8 ak0 = *reinterpret_cast<const bf16x8*>(
                &Ks[cur][kr][((0 + rhi) ^ (kr & 7)) * 8]);
            bf16x8 ak1 = *reinterpret_cast<const bf16x8*>(
                &Ks[cur][kr][((4 + rhi) ^ (kr & 7)) * 8]);
            f32x4 a0 = {};
            a0 = __builtin_amdgcn_mfma_f32_16x16x32_bf16(ak0, aqA[0], a0, 0, 0, 0);
            a0 = __builtin_amdgcn_mfma_f32_16x16x32_bf16(ak1, aqA[1], a0, 0, 0, 0);
            sA[f] = a0;
            if (doB) {
                f32x4 b0 = {};
                b0 = __builtin_amdgcn_mfma_f32_16x16x32_bf16(ak0, aqB[0], b0, 0, 0, 0);
                b0 = __builtin_amdgcn_mfma_f32_16x16x32_bf16(ak1, aqB[1], b0, 0, 0, 0);
                sB[f] = b0;
            }
        }
        __builtin_amdgcn_s_setprio(0);

        if (t == tA) APPLYMASK(sA, qrowA, t * 64);
        SOFTMAX_PV(cur, sA, mA, lAc, oA);
        if (doB) {
            if (t == tB) APPLYMASK(sB, qrowB, t * 64);
            SOFTMAX_PV(cur, sB, mB, lBc, oB);
        }

        // ---- pipeline tail: readers done -> restage freed buffer ->
        // wait only for the OLDEST stage (t+1); t+2's loads stay in flight.
        asm volatile("s_barrier" ::: "memory");
        if (t + 2 < nsteps) {
            STAGE(cur, t + 2);
            asm volatile("s_waitcnt vmcnt(4)" ::: "memory");
        } else {
            asm volatile("s_waitcnt vmcnt(0)" ::: "memory");
        }
        asm volatile("s_barrier" ::: "memory");
    }

    // epilogue: complete the row-sum of l, broadcast, normalize, write
    lAc += __shfl_xor(lAc, 16);
    lAc += __shfl_xor(lAc, 32);
    lBc += __shfl_xor(lBc, 16);
    lBc += __shfl_xor(lBc, 32);

    float lvA[4], lvB[4];
    #pragma unroll
    for (int r = 0; r < 4; r++) {
        lvA[r] = __shfl(lAc, rhi * 4 + r);
        lvB[r] = __shfl(lBc, rhi * 4 + r);
    }
    #pragma unroll
    for (int r = 0; r < 4; r++) {
        float invA = 1.f / lvA[r];
        float invB = 1.f / lvB[r];
        long qrA = (long)tA * 64 + wid * 16 + rhi * 4 + r;
        long qrB = (long)tB * 64 + wid * 16 + rhi * 4 + r;
        #pragma unroll
        for (int fd = 0; fd < 4; fd++) {
            int d = fd * 16 + rlo;
            attout[((long)b * T_ + qrA) * E_ + h * DH_ + d] = (__bf16)(oA[fd][r] * invA);
            attout[((long)b * T_ + qrB) * E_ + h * DH_ + d] = (__bf16)(oB[fd][r] * invB);
        }
    }
}

// ---------------------------------------------------------------- launcher
extern "C" void kernel_launch(void* const* d_in, const int* in_sizes, int n_in,
                              void* d_out, int out_size, void* d_ws, size_t ws_size,
                              hipStream_t stream) {
    const float* x  = (const float*)d_in[0];
    const float* Wq = (const float*)d_in[1];
    const float* Wk = (const float*)d_in[2];
    const float* Wv = (const float*)d_in[3];
    const float* Wp = (const float*)d_in[4];
    const float* bp = (const float*)d_in[5];

    char* ws = (char*)d_ws;
    const long SZ_XE = (long)B_ * T_ * E_ * 2;      // 16 MB (bf16 [B*T][E])
    __bf16* xb   = (__bf16*)(ws);                   // x bf16; REUSED as attout after QKV
    __bf16* qb   = (__bf16*)(ws + SZ_XE);
    __bf16* kb   = (__bf16*)(ws + 2 * SZ_XE);
    __bf16* vt   = (__bf16*)(ws + 3 * SZ_XE);       // V^T: [B*H][DH][T]
    __bf16* wcat = (__bf16*)(ws + 4 * SZ_XE);       // [3072][1024] bf16 (6 MB)
    __bf16* wpb  = (__bf16*)(ws + 4 * SZ_XE + (long)3072 * 1024 * 2);
    __bf16* att  = xb;  // alias: xb dead after QKV GEMM (stream-ordered)

    // fused casts (x, Wp, wcat in one launch)
    cast_all<<<8192, 256, 0, stream>>>(x, Wq, Wk, Wv, Wp, xb, wcat, wpb);

    // fused QKV projection: [8192][1024] @ wcat^T -> q/k [bh][t][d], vt [bh][d][t]
    gemm128<3><<<dim3(64, 24), 256, 0, stream>>>(
        xb, wcat, nullptr, nullptr, qb, kb, vt, E_, 3 * E_);

    // causal attention (exact R8 kernel — best measured)
    attn_kernel<<<dim3(16, B_ * H_), 256, 0, stream>>>(qb, kb, vt, att);

    // output projection + bias (fp32 out)
    gemm128<1><<<dim3(64, 8), 256, 0, stream>>>(
        att, wpb, (float*)d_out, bp, nullptr, nullptr, nullptr, E_, E_);
}